// Round 1
// baseline (373.302 us; speedup 1.0000x reference)
//
#include <hip/hip_runtime.h>
#include <hip/hip_bf16.h>
#include <math.h>

#define B_   32
#define CIN  3
#define H_   224
#define W_   224
#define OC   192
#define OH   112
#define OW   112
#define PH   56
#define PW   56
#define NSP  (B_*OH*OW)          // 401408 elements per channel for BN stats
#define PLANE (OH*OW)            // 12544

static __device__ __forceinline__ unsigned short f2bf(float f) {
    __hip_bfloat16 h = __float2bfloat16(f);   // RNE
    return *reinterpret_cast<unsigned short*>(&h);
}
static __device__ __forceinline__ float bfbits2f(unsigned short u) {
    unsigned int v = ((unsigned int)u) << 16;
    return *reinterpret_cast<float*>(&v);
}

// ---------------- K0: zero the stats accumulators (ws is poisoned 0xAA) ----
__global__ void zero_stats(float* stats) {
    for (int i = threadIdx.x; i < 768; i += 256) stats[i] = 0.f;
}

// ---------------- K1: conv 3x3 s2 p1, bias, write y as bf16 ----------------
// Each thread: 4 consecutive ow positions, ALL 192 oc.
// x taps (3c x 3r x 9cols = 81 f32) live in registers, fully unrolled.
// Weight index depends only on uniform oc -> scalar (s_load) path.
__global__ __launch_bounds__(256) void conv_kernel(
    const float* __restrict__ x, const float* __restrict__ w,
    const float* __restrict__ bias, __hip_bfloat16* __restrict__ y)
{
    int g = blockIdx.x * 256 + threadIdx.x;      // 100352 total
    int owg = g % (OW / 4);
    int t   = g / (OW / 4);
    int oh  = t % OH;
    int b   = t / OH;
    int ow0 = owg * 4;

    int ih0 = 2 * oh  - 1;
    int iw0 = 2 * ow0 - 1;

    float xv[CIN][3][9];
    #pragma unroll
    for (int c = 0; c < CIN; ++c) {
        #pragma unroll
        for (int r = 0; r < 3; ++r) {
            int ih = ih0 + r;
            bool rv = (ih >= 0) && (ih < H_);
            const float* xrow = x + (((size_t)b * CIN + c) * H_ + (rv ? ih : 0)) * W_;
            #pragma unroll
            for (int j = 0; j < 9; ++j) {
                int iw = iw0 + j;
                bool v = rv && (iw >= 0) && (iw < W_);
                xv[c][r][j] = v ? xrow[iw] : 0.f;
            }
        }
    }

    int ybase = (b * OC) * PLANE + oh * OW + ow0;

    for (int oc = 0; oc < OC; ++oc) {
        float bs = bias[oc];
        float a0 = bs, a1 = bs, a2 = bs, a3 = bs;
        const float* wp = w + oc * 27;
        #pragma unroll
        for (int c = 0; c < CIN; ++c)
            #pragma unroll
            for (int r = 0; r < 3; ++r)
                #pragma unroll
                for (int j = 0; j < 3; ++j) {
                    float wv = wp[c * 9 + r * 3 + j];
                    a0 = fmaf(wv, xv[c][r][j + 0], a0);
                    a1 = fmaf(wv, xv[c][r][j + 2], a1);
                    a2 = fmaf(wv, xv[c][r][j + 4], a2);
                    a3 = fmaf(wv, xv[c][r][j + 6], a3);
                }
        ushort4 p;
        p.x = f2bf(a0); p.y = f2bf(a1); p.z = f2bf(a2); p.w = f2bf(a3);
        *reinterpret_cast<ushort4*>(
            reinterpret_cast<unsigned short*>(y) + ybase + oc * PLANE) = p;
    }
}

// ---------------- K2: per-channel sum / sumsq over y ----------------------
__global__ __launch_bounds__(256) void stats_kernel(
    const __hip_bfloat16* __restrict__ y, float* __restrict__ stats)
{
    int plane = blockIdx.x;            // b*OC + oc, 6144 blocks
    int oc = plane % OC;
    const unsigned int* p =
        reinterpret_cast<const unsigned int*>(y) + plane * (PLANE / 2);

    float s = 0.f, s2 = 0.f;
    // 12544 bf16 = 6272 uint (2 bf16 each); read uint4 (8 bf16) per iter
    for (int ch = threadIdx.x; ch < PLANE / 8; ch += 256) {
        uint4 v = reinterpret_cast<const uint4*>(p)[ch];
        unsigned int u[4] = {v.x, v.y, v.z, v.w};
        #pragma unroll
        for (int k = 0; k < 4; ++k) {
            float lo = bfbits2f((unsigned short)(u[k] & 0xffffu));
            float hi = bfbits2f((unsigned short)(u[k] >> 16));
            s  += lo + hi;
            s2 += lo * lo + hi * hi;
        }
    }

    __shared__ float ls[256], ls2[256];
    int tid = threadIdx.x;
    ls[tid] = s; ls2[tid] = s2;
    __syncthreads();
    for (int off = 128; off > 0; off >>= 1) {
        if (tid < off) { ls[tid] += ls[tid + off]; ls2[tid] += ls2[tid + off]; }
        __syncthreads();
    }
    if (tid == 0) {
        atomicAdd(&stats[oc], ls[0]);
        atomicAdd(&stats[192 + oc], ls2[0]);
    }
}

// ---------------- K3: finalize BN -> per-channel scale/shift --------------
__global__ void finalize_kernel(const float* __restrict__ gamma,
                                const float* __restrict__ beta,
                                float* stats)
{
    int i = threadIdx.x;
    if (i < OC) {
        float mean = stats[i] / (float)NSP;
        float var  = stats[192 + i] / (float)NSP - mean * mean;
        float inv  = rsqrtf(var + 1e-5f);
        float sc   = gamma[i] * inv;
        stats[384 + i] = sc;                    // scale
        stats[576 + i] = beta[i] - mean * sc;   // shift
    }
}

// ---------------- K4: BN affine + exact GELU + maxpool 3x3 s2 p1 ----------
__global__ __launch_bounds__(256) void pool_kernel(
    const __hip_bfloat16* __restrict__ y, const float* __restrict__ stats,
    float* __restrict__ out)
{
    int g = blockIdx.x * 256 + threadIdx.x;     // 19267584 total
    int pw = g % PW;
    int t  = g / PW;
    int ph = t % PH;
    t /= PH;
    int oc = t % OC;
    int b  = t / OC;

    const unsigned short* p =
        reinterpret_cast<const unsigned short*>(y) + (b * OC + oc) * PLANE;
    float sc = stats[384 + oc];
    float sh = stats[576 + oc];

    float m = -INFINITY;
    #pragma unroll
    for (int r = 0; r < 3; ++r) {
        int ih = 2 * ph - 1 + r;
        if (ih < 0 || ih >= OH) continue;
        #pragma unroll
        for (int j = 0; j < 3; ++j) {
            int iw = 2 * pw - 1 + j;
            if (iw < 0 || iw >= OW) continue;
            float v = fmaf(bfbits2f(p[ih * OW + iw]), sc, sh);
            float gg = 0.5f * v * (1.f + erff(v * 0.70710678118654752f));
            m = fmaxf(m, gg);
        }
    }
    out[g] = m;
}

extern "C" void kernel_launch(void* const* d_in, const int* in_sizes, int n_in,
                              void* d_out, int out_size, void* d_ws, size_t ws_size,
                              hipStream_t stream) {
    const float* x     = (const float*)d_in[0];
    const float* w     = (const float*)d_in[1];
    const float* bias  = (const float*)d_in[2];
    const float* gamma = (const float*)d_in[3];
    const float* beta  = (const float*)d_in[4];
    float* out = (float*)d_out;

    float* stats = (float*)d_ws;                                   // 768 floats + scale/shift
    __hip_bfloat16* y = (__hip_bfloat16*)((char*)d_ws + 4096);     // 154.1 MB bf16

    hipLaunchKernelGGL(zero_stats, dim3(1), dim3(256), 0, stream, stats);
    hipLaunchKernelGGL(conv_kernel, dim3((B_ * OH * (OW / 4)) / 256), dim3(256), 0, stream,
                       x, w, bias, y);
    hipLaunchKernelGGL(stats_kernel, dim3(B_ * OC), dim3(256), 0, stream, y, stats);
    hipLaunchKernelGGL(finalize_kernel, dim3(1), dim3(256), 0, stream, gamma, beta, stats);
    hipLaunchKernelGGL(pool_kernel, dim3((B_ * OC * PH * PW) / 256), dim3(256), 0, stream,
                       y, stats, out);
}

// Round 3
// 239.278 us; speedup vs baseline: 1.5601x; 1.5601x over previous
//
#include <hip/hip_runtime.h>
#include <hip/hip_bf16.h>
#include <math.h>

#define B_   32
#define CIN  3
#define H_   224
#define W_   224
#define OC   192
#define OH   112
#define OW   112
#define PH   56
#define PW   56
#define NSP  (B_*OH*OW)          // 401408 elements per channel for BN stats
#define PLANE (OH*OW)            // 12544
#define LROW 116                 // padded LDS row stride (floats): 116%32=20 -> <=2-way conflicts
#define LPAD 8                   // leading pad floats (covers col -2 reads, keeps 16B alignment)

static __device__ __forceinline__ unsigned short f2bf(float f) {
    __hip_bfloat16 h = __float2bfloat16(f);   // RNE
    return *reinterpret_cast<unsigned short*>(&h);
}
static __device__ __forceinline__ float bfbits2f(unsigned short u) {
    unsigned int v = ((unsigned int)u) << 16;
    return *reinterpret_cast<float*>(&v);
}

static __device__ __forceinline__ float fexp2(float x) {
#if __has_builtin(__builtin_amdgcn_exp2f)
    return __builtin_amdgcn_exp2f(x);
#else
    return exp2f(x);
#endif
}
static __device__ __forceinline__ float frcp(float x) {
#if __has_builtin(__builtin_amdgcn_rcpf)
    return __builtin_amdgcn_rcpf(x);
#else
    return 1.0f / x;
#endif
}

// tanh-form GELU: x * sigmoid(2*c1*(x + 0.044715 x^3)), evaluated via exp2.
// 2*c1*log2(e) = 2*0.7978845608*1.4426950408 = 2.3022082
static __device__ __forceinline__ float fast_gelu(float x) {
    float x2 = x * x;
    float inner = fmaf(0.044715f * x2, x, x);
    float e = fexp2(inner * 2.3022082f);
    float r = frcp(1.0f + e);
    return x * (e * r);          // no cancellation on the negative tail
}

// ---------------- K0: zero the stats accumulators (ws is poisoned 0xAA) ----
__global__ void zero_stats(float* stats) {
    for (int i = threadIdx.x; i < 768; i += 256) stats[i] = 0.f;
}

// ---------------- K1: conv 3x3 s2 p1, bias, write y as bf16 ----------------
__global__ __launch_bounds__(256) void conv_kernel(
    const float* __restrict__ x, const float* __restrict__ w,
    const float* __restrict__ bias, __hip_bfloat16* __restrict__ y)
{
    int g = blockIdx.x * 256 + threadIdx.x;      // 100352 total
    int owg = g % (OW / 4);
    int t   = g / (OW / 4);
    int oh  = t % OH;
    int b   = t / OH;
    int ow0 = owg * 4;

    int ih0 = 2 * oh  - 1;
    int iw0 = 2 * ow0 - 1;

    float xv[CIN][3][9];
    #pragma unroll
    for (int c = 0; c < CIN; ++c) {
        #pragma unroll
        for (int r = 0; r < 3; ++r) {
            int ih = ih0 + r;
            bool rv = (ih >= 0) && (ih < H_);
            const float* xrow = x + (((size_t)b * CIN + c) * H_ + (rv ? ih : 0)) * W_;
            #pragma unroll
            for (int j = 0; j < 9; ++j) {
                int iw = iw0 + j;
                bool v = rv && (iw >= 0) && (iw < W_);
                xv[c][r][j] = v ? xrow[iw] : 0.f;
            }
        }
    }

    int ybase = (b * OC) * PLANE + oh * OW + ow0;

    for (int oc = 0; oc < OC; ++oc) {
        float bs = bias[oc];
        float a0 = bs, a1 = bs, a2 = bs, a3 = bs;
        const float* wp = w + oc * 27;
        #pragma unroll
        for (int c = 0; c < CIN; ++c)
            #pragma unroll
            for (int r = 0; r < 3; ++r)
                #pragma unroll
                for (int j = 0; j < 3; ++j) {
                    float wv = wp[c * 9 + r * 3 + j];
                    a0 = fmaf(wv, xv[c][r][j + 0], a0);
                    a1 = fmaf(wv, xv[c][r][j + 2], a1);
                    a2 = fmaf(wv, xv[c][r][j + 4], a2);
                    a3 = fmaf(wv, xv[c][r][j + 6], a3);
                }
        ushort4 p;
        p.x = f2bf(a0); p.y = f2bf(a1); p.z = f2bf(a2); p.w = f2bf(a3);
        *reinterpret_cast<ushort4*>(
            reinterpret_cast<unsigned short*>(y) + ybase + oc * PLANE) = p;
    }
}

// ---------------- K2: per-channel sum / sumsq over y ----------------------
__global__ __launch_bounds__(256) void stats_kernel(
    const __hip_bfloat16* __restrict__ y, float* __restrict__ stats)
{
    int plane = blockIdx.x;            // b*OC + oc, 6144 blocks
    int oc = plane % OC;
    const unsigned int* p =
        reinterpret_cast<const unsigned int*>(y) + plane * (PLANE / 2);

    float s = 0.f, s2 = 0.f;
    for (int ch = threadIdx.x; ch < PLANE / 8; ch += 256) {
        uint4 v = reinterpret_cast<const uint4*>(p)[ch];
        unsigned int u[4] = {v.x, v.y, v.z, v.w};
        #pragma unroll
        for (int k = 0; k < 4; ++k) {
            float lo = bfbits2f((unsigned short)(u[k] & 0xffffu));
            float hi = bfbits2f((unsigned short)(u[k] >> 16));
            s  += lo + hi;
            s2 += lo * lo + hi * hi;
        }
    }

    __shared__ float ls[256], ls2[256];
    int tid = threadIdx.x;
    ls[tid] = s; ls2[tid] = s2;
    __syncthreads();
    for (int off = 128; off > 0; off >>= 1) {
        if (tid < off) { ls[tid] += ls[tid + off]; ls2[tid] += ls2[tid + off]; }
        __syncthreads();
    }
    if (tid == 0) {
        atomicAdd(&stats[oc], ls[0]);
        atomicAdd(&stats[192 + oc], ls2[0]);
    }
}

// ---------------- K3: BN(affine)+GELU once per element (LDS) + maxpool ----
// One block per (b,oc) plane. 448 threads = 7 waves.
// Phase 1: 3136 groups of 4 bf16 -> BN+fast_gelu -> f32 LDS (padded rows).
// Phase 2: 56 rows x 8 col-groups, 7 outputs each; vertical max then horiz.
__global__ __launch_bounds__(448) void pool_kernel(
    const __hip_bfloat16* __restrict__ y, const float* __restrict__ stats,
    const float* __restrict__ gamma, const float* __restrict__ beta,
    float* __restrict__ out)
{
    __shared__ float g[LPAD + OH * LROW];        // 8 + 112*116 = 13000 floats = 52 KB

    int plane = blockIdx.x;                      // b*OC + oc
    int oc = plane % OC;

    // finalize BN scale/shift from raw sums (cheap, per block)
    float mean = stats[oc] * (1.0f / (float)NSP);
    float var  = fmaf(-mean, mean, stats[192 + oc] * (1.0f / (float)NSP));
    float inv  = rsqrtf(var + 1e-5f);
    float sc   = gamma[oc] * inv;
    float sh   = fmaf(-mean, sc, beta[oc]);

    const uint2* p = reinterpret_cast<const uint2*>(
        reinterpret_cast<const unsigned short*>(y) + (size_t)plane * PLANE);

    int t = threadIdx.x;
    // ---- phase 1: 3136 4-elem groups / 448 threads = 7 exact iterations ----
    #pragma unroll
    for (int it = 0; it < 7; ++it) {
        int gi = it * 448 + t;
        uint2 v = p[gi];
        int row = gi / 28;                       // 112 cols = 28 groups/row
        int col = (gi - row * 28) * 4;
        float4 q;
        q.x = fast_gelu(fmaf(bfbits2f((unsigned short)(v.x & 0xffffu)), sc, sh));
        q.y = fast_gelu(fmaf(bfbits2f((unsigned short)(v.x >> 16)),     sc, sh));
        q.z = fast_gelu(fmaf(bfbits2f((unsigned short)(v.y & 0xffffu)), sc, sh));
        q.w = fast_gelu(fmaf(bfbits2f((unsigned short)(v.y >> 16)),     sc, sh));
        *reinterpret_cast<float4*>(&g[LPAD + row * LROW + col]) = q;   // 16B aligned
    }
    __syncthreads();

    // ---- phase 2: r = output row (0..55), k = col-group (0..7), 7 outputs --
    int r = t >> 3;
    int k = t & 7;
    int c0 = 14 * k - 2;                         // even -> float2 aligned

    float vm[16];
    #pragma unroll
    for (int q = 0; q < 16; ++q) vm[q] = -INFINITY;

    #pragma unroll
    for (int rr = 0; rr < 3; ++rr) {
        int row = 2 * r - 1 + rr;
        if (row < 0) continue;                   // only r==0, rr==0; row<=111 always
        const float2* rp = reinterpret_cast<const float2*>(&g[LPAD + row * LROW + c0]);
        #pragma unroll
        for (int q = 0; q < 8; ++q) {
            float2 v = rp[q];
            vm[2 * q]     = fmaxf(vm[2 * q],     v.x);
            vm[2 * q + 1] = fmaxf(vm[2 * q + 1], v.y);
        }
    }
    if (k == 0) vm[1] = -INFINITY;               // col -1 is out of bounds

    float* op = out + (size_t)plane * (PH * PW) + r * PW + 7 * k;
    #pragma unroll
    for (int m = 0; m < 7; ++m) {
        op[m] = fmaxf(fmaxf(vm[2 * m + 1], vm[2 * m + 2]), vm[2 * m + 3]);
    }
}

extern "C" void kernel_launch(void* const* d_in, const int* in_sizes, int n_in,
                              void* d_out, int out_size, void* d_ws, size_t ws_size,
                              hipStream_t stream) {
    const float* x     = (const float*)d_in[0];
    const float* w     = (const float*)d_in[1];
    const float* bias  = (const float*)d_in[2];
    const float* gamma = (const float*)d_in[3];
    const float* beta  = (const float*)d_in[4];
    float* out = (float*)d_out;

    float* stats = (float*)d_ws;                                   // 384 floats of sums
    __hip_bfloat16* y = (__hip_bfloat16*)((char*)d_ws + 4096);     // 154.1 MB bf16

    hipLaunchKernelGGL(zero_stats, dim3(1), dim3(256), 0, stream, stats);
    hipLaunchKernelGGL(conv_kernel, dim3((B_ * OH * (OW / 4)) / 256), dim3(256), 0, stream,
                       x, w, bias, y);
    hipLaunchKernelGGL(stats_kernel, dim3(B_ * OC), dim3(256), 0, stream, y, stats);
    hipLaunchKernelGGL(pool_kernel, dim3(B_ * OC), dim3(448), 0, stream,
                       y, stats, gamma, beta, out);
}